// Round 21
// baseline (71.113 us; speedup 1.0000x reference)
//
#include <hip/hip_runtime.h>
#include <hip/hip_bf16.h>
#include <stdint.h>

// Problem constants
#define B_ 16
#define C_ 256
#define H_ 64
#define W_ 64
#define WP 66                   // padded width: w' = w+1, border cols 0 and 65 zero
#define ROWB (WP * 128)         // bytes per padded row of fp4 signs = 8448
#define STAGEB (3 * ROWB)       // 3 rows staged = 25344

typedef __attribute__((ext_vector_type(4))) float f32x4;
typedef __attribute__((ext_vector_type(4))) int int4v;
typedef __attribute__((ext_vector_type(8))) int int8v;

// fp4 e2m1 signs: +1 = 0x2, -1 = 0xA, 0 = 0x0 (exact)
__device__ __forceinline__ uint8_t sgn4(float v) {
  return v > 0.f ? (uint8_t)0x2 : (v < 0.f ? (uint8_t)0xA : (uint8_t)0);
}

// fp4 uses only the low 4 regs of the 8-reg f8f6f4 operand; upper 4 undef.
#define EXT8(v4) __builtin_shufflevector((v4), (v4), 0, 1, 2, 3, -1, -1, -1, -1)

// ---------- kernel A: weight scale + fp4 signs, K=128 scaled-MFMA layout ----------
// wtb[t][ot][kh][mi][lane][16B] ; lane's 32-element (16B) fp4 A-frag.
// o = ot*64 + mi*16 + (l&15), c = kh*128 + (l>>4)*32 + j (nibble j of 16B)
__global__ void prep_w(const float* __restrict__ w, float* __restrict__ scale,
                       uint8_t* __restrict__ wtb) {
  int o = blockIdx.x, c = threadIdx.x;
  const float* wo = w + (size_t)o * 2304 + (size_t)c * 9;  // w[o][c][kh][kw]
  float v[9];
  float s = 0.f;
#pragma unroll
  for (int t = 0; t < 9; ++t) { v[t] = wo[t]; s += fabsf(v[t]); }
  __shared__ float red[256];
  __shared__ uint8_t sg[9][256];
  red[c] = s;
#pragma unroll
  for (int t = 0; t < 9; ++t) sg[t][c] = sgn4(v[t]);
  __syncthreads();
  for (int st = 128; st > 0; st >>= 1) {
    if (c < st) red[c] += red[c + st];
    __syncthreads();
  }
  if (c == 0) scale[o] = red[0] / 2304.0f;
  if (c < 128) {               // thread c packs channels 2c, 2c+1 into one byte
    int k = c;
    int ot = o >> 6, mi = (o >> 4) & 3, lm = o & 15;
    int kh = k >> 6, lk = (k >> 4) & 3, jb = k & 15;
    int l = lk * 16 + lm;
#pragma unroll
    for (int t = 0; t < 9; ++t) {
      uint8_t byte = (uint8_t)(sg[t][2 * k] | (sg[t][2 * k + 1] << 4));
      wtb[((((size_t)t * 4 + ot) * 2 + kh) * 4 + mi) * 1024 + l * 16 + jb] = byte;
    }
  }
}

// ---------- kernel B (FUSED): binarize 3 rows into LDS + MX-fp4 MFMA conv ----------
// Round-21: binarize fused into bconv. Each block transposes+packs its own 3
// input rows (h-1,h,h+1) straight into the swizzled LDS staging buffer; a_p
// and the separate binarize kernel are deleted. Redundant 3x row work is
// L2/L3-served (x L3-resident; neighbor bh blocks share rows on one XCD).
// Main loop/epilogue = r19 verified code (W ping-pong, B JIT).
#define LOADW(dst, t, kh) {                                                       \
  const uint8_t* wb_ = wtb + ((((size_t)(t) * 4 + wv) * 2 + (kh)) * 4) * 1024 + l * 16; \
  _Pragma("unroll") for (int mi = 0; mi < 4; ++mi)                                \
      dst[mi] = *(const int4v*)(wb_ + mi * 1024); }

#define LOADB(dst, d, dxi, kh) {                                                  \
  int ch_ = (kh) * 4 + lk;                                                        \
  _Pragma("unroll") for (int ni = 0; ni < 4; ++ni) {                              \
    int wp_ = ni * 16 + lm + (dxi);                                               \
    dst[ni] = *(const int4v*)(smem + (d) * ROWB + wp_ * 128 +                     \
                              (((ch_ ^ wp_) & 7) << 4)); } }

#define MFMA_BURST(wreg)                                                          \
  __builtin_amdgcn_s_setprio(1);                                                  \
  _Pragma("unroll") for (int mi = 0; mi < 4; ++mi)                                \
    _Pragma("unroll") for (int ni = 0; ni < 4; ++ni)                              \
      acc[mi][ni] = __builtin_amdgcn_mfma_scale_f32_16x16x128_f8f6f4(             \
          EXT8(wreg[mi]), EXT8(bf[ni]), acc[mi][ni], 4, 4, 0, 127, 0, 127);       \
  __builtin_amdgcn_s_setprio(0);

__global__ __launch_bounds__(256, 3) void bconv(
    const uint8_t* __restrict__ wtb, const float* __restrict__ scale,
    const float* __restrict__ x, const float* __restrict__ m0b,
    const float* __restrict__ pb0, const float* __restrict__ alpha,
    const float* __restrict__ pb1, float* __restrict__ out) {
  __shared__ __attribute__((aligned(16))) uint8_t smem[STAGEB];
  __shared__ uint8_t lt[64][268];  // [w][ci] transpose buffer, stride 268 (bank spread)
  // XCD-aware bijective swizzle: 1024 blocks, 8 XCDs, 128 contiguous per XCD
  int bh = (blockIdx.x & 7) * 128 + (blockIdx.x >> 3);
  int b = bh >> 6, h = bh & 63;
  int tid = threadIdx.x, l = tid & 63, wv = tid >> 6;
  int lm = l & 15, lk = l >> 4;
  int wm = wv * 64;

  // ---- Phase 1: binarize input rows h-1,h,h+1 into swizzled fp4 staging ----
  // Per row: coalesced f32x4 x-reads -> lt[w][ci] -> nibble-pack 8 channels/u32
  // -> swizzled store (chunk ^= wp&7). OOB rows and border pixels are zeros.
#pragma unroll 1
  for (int r = 0; r < 3; ++r) {
    int hr = h - 1 + r;
    bool valid = (hr >= 0) && (hr < H_);
    if (valid) {
#pragma unroll
      for (int p = 0; p < 16; ++p) {
        int ci = p * 16 + (tid >> 4), w4 = (tid & 15) * 4;
        f32x4 v = *(const f32x4*)(x + (((size_t)(b * C_ + ci) * H_ + hr) * W_ + w4));
        float bb = m0b[ci];
#pragma unroll
        for (int k = 0; k < 4; ++k) lt[w4 + k][ci] = sgn4(v[k] + bb);
      }
    }
    __syncthreads();
    int q = tid & 31;  // u32-chunk: channels q*8..q*8+7 (fixed per thread)
#pragma unroll
    for (int rr = 0; rr < 8; ++rr) {
      int u = rr * 256 + tid, w = u >> 5;
      uint32_t val = 0;
      if (valid) {
        uint32_t a0 = *(const uint32_t*)&lt[w][q * 8];
        uint32_t a1 = *(const uint32_t*)&lt[w][q * 8 + 4];
        val = (a0 & 0xFu) | ((a0 >> 4) & 0xF0u) | ((a0 >> 8) & 0xF00u) |
              ((a0 >> 12) & 0xF000u);
        val |= ((a1 & 0xFu) | ((a1 >> 4) & 0xF0u) | ((a1 >> 8) & 0xF00u) |
                ((a1 >> 12) & 0xF000u)) << 16;
      }
      int wp = w + 1;
      *(uint32_t*)(smem + r * ROWB + wp * 128 + ((((q >> 2) ^ wp) & 7) << 4) +
                   (q & 3) * 4) = val;
    }
    if (tid < 64) {  // border pixels wp=0 and wp=65 (zeros are swizzle-invariant)
      int px = (tid >> 5) ? 65 : 0;
      *(uint32_t*)(smem + r * ROWB + px * 128 + (tid & 31) * 4) = 0;
    }
    __syncthreads();
  }

  f32x4 acc[4][4];
#pragma unroll
  for (int i = 0; i < 4; ++i)
#pragma unroll
    for (int j = 0; j < 4; ++j) acc[i][j] = (f32x4){0.f, 0.f, 0.f, 0.f};

  // ---- Phase 2: r19 main loop (W ping-pong, B JIT from LDS) ----
  int4v wA[4], wB[4], bf[4];
  LOADW(wA, 0, 0)
#pragma unroll 1
  for (int t = 0; t < 9; ++t) {      // tap loop NOT unrolled: fences code motion
    int d = t / 3, dxi = t - d * 3;
    // step kh=0: prefetch (t,1) into wB, B JIT, burst with wA
    LOADW(wB, t, 1)
    LOADB(bf, d, dxi, 0)
    MFMA_BURST(wA)
    // step kh=1: prefetch (t+1,0) into wA, B JIT, burst with wB
    if (t < 8) { LOADW(wA, t + 1, 0) }
    LOADB(bf, d, dxi, 1)
    MFMA_BURST(wB)
  }

  // epilogue: conv*scale + pb0 -> PReLU -> + pb1 + x (residual)
  size_t xb = (size_t)b * C_ * H_ * W_ + (size_t)h * W_;
#pragma unroll
  for (int mi = 0; mi < 4; ++mi) {
#pragma unroll
    for (int j = 0; j < 4; ++j) {
      int o = wm + mi * 16 + lk * 4 + j;  // C/D row = (lane>>4)*4 + reg
      float sc = scale[o], b0 = pb0[o], al = alpha[o], b1 = pb1[o];
      size_t rowo = xb + (size_t)o * (H_ * W_);
#pragma unroll
      for (int ni = 0; ni < 4; ++ni) {
        int wcol = ni * 16 + lm;          // C/D col = lane&15
        float v = acc[mi][ni][j] * sc + b0;
        v = v >= 0.f ? v : al * v;
        v = v + b1 + x[rowo + wcol];
        out[rowo + wcol] = v;
      }
    }
  }
}

extern "C" void kernel_launch(void* const* d_in, const int* in_sizes, int n_in,
                              void* d_out, int out_size, void* d_ws, size_t ws_size,
                              hipStream_t stream) {
  const float* x     = (const float*)d_in[0];
  const float* m0b   = (const float*)d_in[1];
  const float* w     = (const float*)d_in[2];
  const float* pb0   = (const float*)d_in[3];
  const float* alpha = (const float*)d_in[4];
  const float* pb1   = (const float*)d_in[5];
  float* out = (float*)d_out;

  // ws: [0,4KB) scale | [4096, +294912) wtb fp4. (a_p deleted - binarize fused)
  float* scale = (float*)d_ws;
  uint8_t* wtb = (uint8_t*)d_ws + 4096;

  hipLaunchKernelGGL(prep_w, dim3(C_), dim3(256), 0, stream, w, scale, wtb);
  hipLaunchKernelGGL(bconv, dim3(B_ * H_), dim3(256), 0, stream,
                     wtb, scale, x, m0b, pb0, alpha, pb1, out);
}

// Round 22
// 50.369 us; speedup vs baseline: 1.4118x; 1.4118x over previous
//
#include <hip/hip_runtime.h>
#include <hip/hip_bf16.h>
#include <stdint.h>

// Problem constants
#define B_ 16
#define C_ 256
#define H_ 64
#define W_ 64
#define WP 66                   // padded width: w' = w+1, border cols 0 and 65 zero
#define HP 66                   // padded height: h' = h+1, border rows 0 and 65 zero
#define ROWB (WP * 128)         // bytes per padded row of fp4 signs = 8448
#define STAGEB (3 * ROWB + 32)  // 3 rows staged + pad = 25376

typedef __attribute__((ext_vector_type(4))) float f32x4;
typedef __attribute__((ext_vector_type(4))) int int4v;
typedef __attribute__((ext_vector_type(8))) int int8v;

typedef const __attribute__((address_space(1))) uint32_t* gptr_t;
typedef __attribute__((address_space(3))) uint32_t* lptr_t;

__device__ __forceinline__ void gl_lds16(const void* g, void* l) {
  __builtin_amdgcn_global_load_lds((gptr_t)g, (lptr_t)l, 16, 0, 0);
}

// fp4 e2m1 signs: +1 = 0x2, -1 = 0xA, 0 = 0x0 (exact)
__device__ __forceinline__ uint8_t sgn4(float v) {
  return v > 0.f ? (uint8_t)0x2 : (v < 0.f ? (uint8_t)0xA : (uint8_t)0);
}

// fp4 uses only the low 4 regs of the 8-reg f8f6f4 operand; upper 4 undef.
#define EXT8(v4) __builtin_shufflevector((v4), (v4), 0, 1, 2, 3, -1, -1, -1, -1)

// ---------- kernel A (MERGED): prep_w (blocks 0..255) + binarize (blocks 256..4351) ----------
// prep_w: wtb[t][ot][kh][mi][lane][16B]; o = ot*64+mi*16+(l&15),
//         c = kh*128+(l>>4)*32+j. binarize: a_p row b*66+(h+1), 66 blocks of
//         128B = 8 chunks of 16B, chunk=(c>>5), stored chunk ^= (w'&7).
__global__ void prep_and_binarize(const float* __restrict__ w,
                                  float* __restrict__ scale,
                                  uint8_t* __restrict__ wtb,
                                  const float* __restrict__ x,
                                  const float* __restrict__ bias,
                                  uint8_t* __restrict__ a_p) {
  int tid = threadIdx.x;
  if (blockIdx.x < 256) {  // ---- prep_w ----
    int o = blockIdx.x, c = tid;
    const float* wo = w + (size_t)o * 2304 + (size_t)c * 9;  // w[o][c][kh][kw]
    float v[9];
    float s = 0.f;
#pragma unroll
    for (int t = 0; t < 9; ++t) { v[t] = wo[t]; s += fabsf(v[t]); }
    __shared__ float red[256];
    __shared__ uint8_t sg[9][256];
    red[c] = s;
#pragma unroll
    for (int t = 0; t < 9; ++t) sg[t][c] = sgn4(v[t]);
    __syncthreads();
    for (int st = 128; st > 0; st >>= 1) {
      if (c < st) red[c] += red[c + st];
      __syncthreads();
    }
    if (c == 0) scale[o] = red[0] / 2304.0f;
    if (c < 128) {  // thread c packs channels 2c, 2c+1 into one byte
      int k = c;
      int ot = o >> 6, mi = (o >> 4) & 3, lm = o & 15;
      int kh = k >> 6, lk = (k >> 4) & 3, jb = k & 15;
      int l = lk * 16 + lm;
#pragma unroll
      for (int t = 0; t < 9; ++t) {
        uint8_t byte = (uint8_t)(sg[t][2 * k] | (sg[t][2 * k + 1] << 4));
        wtb[((((size_t)t * 4 + ot) * 2 + kh) * 4 + mi) * 1024 + l * 16 + jb] = byte;
      }
    }
    return;
  }
  // ---- binarize ----
  int id = blockIdx.x - 256;
  int bh = id >> 2, b = bh >> 6, h = bh & 63, c0 = (id & 3) * 64;
  __shared__ uint8_t lt[64][72];  // [w][ci], sgn4 value in low nibble
#pragma unroll
  for (int p = 0; p < 4; ++p) {
    int ci = p * 16 + (tid >> 4), w4 = (tid & 15) * 4;
    f32x4 v = *(const f32x4*)(x + (((size_t)(b * C_ + c0 + ci) * H_ + h) * W_ + w4));
    float bb = bias[c0 + ci];
#pragma unroll
    for (int k = 0; k < 4; ++k) lt[w4 + k][ci] = sgn4(v[k] + bb);
  }
  __syncthreads();
  size_t rowbase = (size_t)(b * HP + h + 1) * ROWB;
#pragma unroll
  for (int r = 0; r < 2; ++r) {
    int u = r * 256 + tid;             // 0..511 ; this y-block: 64 px x 8 u32
    int w_ = u >> 3, q = u & 7;        // q-th u32 (8 channels) of pixel w
    uint32_t val = 0;
#pragma unroll
    for (int e = 0; e < 8; ++e)
      val |= (uint32_t)(lt[w_][q * 8 + e] & 15) << (4 * e);
    int wp = w_ + 1;
    int ch = (c0 + q * 8) >> 5;
    int pos = wp * 128 + (((ch ^ wp) & 7) << 4) + (q & 3) * 4;
    *(uint32_t*)(a_p + rowbase + pos) = val;
  }
  // zero border pixel blocks; for edge h, zero the padded border rows.
  if ((id & 3) == 0) {
    if (tid < 32) *(uint32_t*)(a_p + rowbase + tid * 4) = 0;
    else if (tid < 64) *(uint32_t*)(a_p + rowbase + 65 * 128 + (tid - 32) * 4) = 0;
  }
  if (h == 0) {  // zero row h'=0 (quarter per y-block)
    uint32_t* zr = (uint32_t*)(a_p + (size_t)b * HP * ROWB) + (id & 3) * 528;
    for (int k = tid; k < 528; k += 256) zr[k] = 0;
  } else if (h == 63) {  // zero row h'=65
    uint32_t* zr = (uint32_t*)(a_p + ((size_t)b * HP + 65) * ROWB) + (id & 3) * 528;
    for (int k = tid; k < 528; k += 256) zr[k] = 0;
  }
}

// ---------- kernel B: binary conv, MX-fp4 MFMA, int4v frags + W ping-pong ----------
// r19 verified best (53.9 us total). W prefetched one step ahead; B JIT from
// swizzled LDS. r20 (B-pp) and r21 (fused binarize) both regressed — this
// structure is the converged optimum of the explored space.
#define LOADW(dst, t, kh) {                                                       \
  const uint8_t* wb_ = wtb + ((((size_t)(t) * 4 + wv) * 2 + (kh)) * 4) * 1024 + l * 16; \
  _Pragma("unroll") for (int mi = 0; mi < 4; ++mi)                                \
      dst[mi] = *(const int4v*)(wb_ + mi * 1024); }

#define LOADB(dst, d, dxi, kh) {                                                  \
  int ch_ = (kh) * 4 + lk;                                                        \
  _Pragma("unroll") for (int ni = 0; ni < 4; ++ni) {                              \
    int wp_ = ni * 16 + lm + (dxi);                                               \
    dst[ni] = *(const int4v*)(smem + (d) * ROWB + wp_ * 128 +                     \
                              (((ch_ ^ wp_) & 7) << 4)); } }

#define MFMA_BURST(wreg)                                                          \
  __builtin_amdgcn_s_setprio(1);                                                  \
  _Pragma("unroll") for (int mi = 0; mi < 4; ++mi)                                \
    _Pragma("unroll") for (int ni = 0; ni < 4; ++ni)                              \
      acc[mi][ni] = __builtin_amdgcn_mfma_scale_f32_16x16x128_f8f6f4(             \
          EXT8(wreg[mi]), EXT8(bf[ni]), acc[mi][ni], 4, 4, 0, 127, 0, 127);       \
  __builtin_amdgcn_s_setprio(0);

__global__ __launch_bounds__(256, 3) void bconv(
    const uint8_t* __restrict__ a_p, const uint8_t* __restrict__ wtb,
    const float* __restrict__ scale, const float* __restrict__ x,
    const float* __restrict__ pb0, const float* __restrict__ alpha,
    const float* __restrict__ pb1, float* __restrict__ out) {
  __shared__ __attribute__((aligned(16))) uint8_t smem[STAGEB];
  // XCD-aware bijective swizzle: 1024 blocks, 8 XCDs, 128 contiguous per XCD
  int bh = (blockIdx.x & 7) * 128 + (blockIdx.x >> 3);
  int b = bh >> 6, h = bh & 63;
  int tid = threadIdx.x, l = tid & 63, wv = tid >> 6;
  int lm = l & 15, lk = l >> 4;
  int wm = wv * 64;

  // stage 3 contiguous padded rows (h', h'+1, h'+2) = input rows h-1,h,h+1
  const uint8_t* src = a_p + (size_t)(b * HP + h) * ROWB;
#pragma unroll
  for (int it = 0; it < 6; ++it)
    gl_lds16(src + (size_t)(it * 256 + tid) * 16, smem + it * 4096 + wv * 1024);
  if (tid < 48) gl_lds16(src + 24576 + (size_t)tid * 16, smem + 24576);

  f32x4 acc[4][4];
#pragma unroll
  for (int i = 0; i < 4; ++i)
#pragma unroll
    for (int j = 0; j < 4; ++j) acc[i][j] = (f32x4){0.f, 0.f, 0.f, 0.f};

  asm volatile("s_waitcnt vmcnt(0)" ::: "memory");
  __syncthreads();

  int4v wA[4], wB[4], bf[4];
  LOADW(wA, 0, 0)
#pragma unroll 1
  for (int t = 0; t < 9; ++t) {      // tap loop NOT unrolled: fences code motion
    int d = t / 3, dxi = t - d * 3;
    // step kh=0: prefetch (t,1) into wB, B JIT, burst with wA
    LOADW(wB, t, 1)
    LOADB(bf, d, dxi, 0)
    MFMA_BURST(wA)
    // step kh=1: prefetch (t+1,0) into wA, B JIT, burst with wB
    if (t < 8) { LOADW(wA, t + 1, 0) }
    LOADB(bf, d, dxi, 1)
    MFMA_BURST(wB)
  }

  // epilogue: conv*scale + pb0 -> PReLU -> + pb1 + x (residual)
  size_t xb = (size_t)b * C_ * H_ * W_ + (size_t)h * W_;
#pragma unroll
  for (int mi = 0; mi < 4; ++mi) {
#pragma unroll
    for (int j = 0; j < 4; ++j) {
      int o = wm + mi * 16 + lk * 4 + j;  // C/D row = (lane>>4)*4 + reg
      float sc = scale[o], b0 = pb0[o], al = alpha[o], b1 = pb1[o];
      size_t rowo = xb + (size_t)o * (H_ * W_);
#pragma unroll
      for (int ni = 0; ni < 4; ++ni) {
        int wcol = ni * 16 + lm;          // C/D col = lane&15
        float v = acc[mi][ni][j] * sc + b0;
        v = v >= 0.f ? v : al * v;
        v = v + b1 + x[rowo + wcol];
        out[rowo + wcol] = v;
      }
    }
  }
}

extern "C" void kernel_launch(void* const* d_in, const int* in_sizes, int n_in,
                              void* d_out, int out_size, void* d_ws, size_t ws_size,
                              hipStream_t stream) {
  const float* x     = (const float*)d_in[0];
  const float* m0b   = (const float*)d_in[1];
  const float* w     = (const float*)d_in[2];
  const float* pb0   = (const float*)d_in[3];
  const float* alpha = (const float*)d_in[4];
  const float* pb1   = (const float*)d_in[5];
  float* out = (float*)d_out;

  // ws: [0,4KB) scale | [4096, +294912+pad) wtb fp4 | a_p padded 16*66*8448 = 8.9MB
  float* scale = (float*)d_ws;
  uint8_t* wtb = (uint8_t*)d_ws + 4096;
  uint8_t* a_p = (uint8_t*)d_ws + 4096 + (size_t)9 * 4 * 2 * 4 * 1024 + 1024;

  hipLaunchKernelGGL(prep_and_binarize, dim3(256 + B_ * H_ * 4), dim3(256), 0,
                     stream, w, scale, wtb, x, m0b, a_p);
  hipLaunchKernelGGL(bconv, dim3(B_ * H_), dim3(256), 0, stream,
                     a_p, wtb, scale, x, pb0, alpha, pb1, out);
}